// Round 4
// baseline (176.422 us; speedup 1.0000x reference)
//
#include <hip/hip_runtime.h>

typedef _Float16 f16;
typedef __attribute__((ext_vector_type(8))) _Float16 f16x8;
typedef __attribute__((ext_vector_type(4))) float f32x4;

#define SEQ   4096
#define NH    16
#define HD    80
#define HIDN  1280
#define DP    96
#define KROWS 104
#define VROWS 56
#define PROWS 56

// 8-phase GEMM constants (QKV: M=4096, N=3840, K=1280)
#define KQ   1280
#define NQ   3840
#define NIT  10      // K / 128

__device__ __forceinline__ void gload16(const void* g, void* l) {
  __builtin_amdgcn_global_load_lds(
      (const __attribute__((address_space(1))) unsigned int*)g,
      (__attribute__((address_space(3))) unsigned int*)l, 16, 0, 0);
}

#define BAR() __builtin_amdgcn_s_barrier()
#define VMCNT(n) do { asm volatile("s_waitcnt vmcnt(" #n ")" ::: "memory"); \
                      __builtin_amdgcn_sched_barrier(0); } while (0)
#define STG(Lb, g, buf, h, kt)                                                  \
  do {                                                                          \
    gload16((g) + (size_t)((h) * 128) * KQ + (kt) * 64,                         \
            (Lb) + (buf) * 16384 + ((h) * 128) * 64 + w * 512);                 \
    gload16((g) + (size_t)((h) * 128 + 64) * KQ + (kt) * 64,                    \
            (Lb) + (buf) * 16384 + ((h) * 128 + 64) * 64 + w * 512);            \
  } while (0)
#define MFQ(IOFF, JOFF, BB)                                                     \
  do {                                                                          \
    __builtin_amdgcn_s_setprio(1);                                              \
    _Pragma("unroll")                                                           \
    for (int i_ = 0; i_ < 4; i_++)                                              \
      _Pragma("unroll")                                                         \
      for (int j_ = 0; j_ < 2; j_++)                                            \
        _Pragma("unroll")                                                       \
        for (int s_ = 0; s_ < 2; s_++)                                          \
          acc[i_ + IOFF][j_ + JOFF] = __builtin_amdgcn_mfma_f32_16x16x32_f16(   \
              a[i_][s_], BB[j_][s_], acc[i_ + IOFF][j_ + JOFF], 0, 0, 0);       \
    __builtin_amdgcn_s_setprio(0);                                              \
  } while (0)

// ---------------- f32 -> f16 convert (n % 8 == 0) ----------------
__global__ __launch_bounds__(256) void cvt_kernel(const float* __restrict__ s,
                                                  f16* __restrict__ d, int n) {
  int base = (blockIdx.x * 256 + threadIdx.x) * 8;
  if (base >= n) return;
  f32x4 v0 = *(const f32x4*)(s + base);
  f32x4 v1 = *(const f32x4*)(s + base + 4);
  f16x8 o;
#pragma unroll
  for (int j = 0; j < 4; j++) { o[j] = (f16)v0[j]; o[4 + j] = (f16)v1[j]; }
  *(f16x8*)(d + base) = o;
}

// ---------------- 8-phase 256^2 GEMM: C[4096][3840] = A * B^T + bias (f16 out) ----
__global__ __launch_bounds__(512, 2) void qkv_gemm8(const f16* __restrict__ A,
                                                    const f16* __restrict__ B,
                                                    const float* __restrict__ bias,
                                                    f16* __restrict__ C) {
  __shared__ __align__(16) f16 LA[2 * 16384];
  __shared__ __align__(16) f16 LB[2 * 16384];
  const int tid = threadIdx.x, w = tid >> 6, l = tid & 63;
  const int bid = (blockIdx.x & 7) * 30 + (blockIdx.x >> 3);
  const int bx = bid % 15, by = bid / 15;
  const int m0 = by * 256, n0 = bx * 256;
  const int wm = (w >> 2) * 128, wn = (w & 3) * 64;
  const int fr = l & 15, fq = l >> 4;
  const int rx = fr & 7;
  const int cA0 = (fq ^ rx) * 8;
  const int cA1 = ((4 + fq) ^ rx) * 8;

  const int srow = w * 8 + (l >> 3);
  const int scol = ((l & 7) ^ (l >> 3)) * 8;
  const f16* gA = A + (size_t)(m0 + srow) * KQ + scol;
  const f16* gB = B + (size_t)(n0 + srow) * KQ + scol;

  f32x4 acc[8][4] = {};
  f16x8 a[4][2], b0[2][2], b1[2][2];

  STG(LA, gA, 0, 0, 0); STG(LA, gA, 0, 1, 0);
  STG(LB, gB, 0, 0, 0); STG(LB, gB, 0, 1, 0);
  STG(LB, gB, 1, 0, 1); STG(LB, gB, 1, 1, 1);
  VMCNT(4);
  BAR();

  for (int it = 0; it < NIT; ++it) {
    const int t = 2 * it;
    const bool lastit = (it == NIT - 1);

#pragma unroll
    for (int i = 0; i < 4; i++) {
      a[i][0] = *(const f16x8*)(LA + (wm + i * 16 + fr) * 64 + cA0);
      a[i][1] = *(const f16x8*)(LA + (wm + i * 16 + fr) * 64 + cA1);
    }
#pragma unroll
    for (int j = 0; j < 2; j++) {
      b0[j][0] = *(const f16x8*)(LB + (wn + j * 16 + fr) * 64 + cA0);
      b0[j][1] = *(const f16x8*)(LB + (wn + j * 16 + fr) * 64 + cA1);
    }
    STG(LA, gA, 1, 0, t + 1);
    BAR(); MFQ(0, 0, b0); BAR();

#pragma unroll
    for (int j = 0; j < 2; j++) {
      b1[j][0] = *(const f16x8*)(LB + (wn + 32 + j * 16 + fr) * 64 + cA0);
      b1[j][1] = *(const f16x8*)(LB + (wn + 32 + j * 16 + fr) * 64 + cA1);
    }
    STG(LA, gA, 1, 1, t + 1);
    BAR(); MFQ(0, 2, b1); BAR();

#pragma unroll
    for (int i = 0; i < 4; i++) {
      a[i][0] = *(const f16x8*)(LA + (wm + 64 + i * 16 + fr) * 64 + cA0);
      a[i][1] = *(const f16x8*)(LA + (wm + 64 + i * 16 + fr) * 64 + cA1);
    }
    if (!lastit) { STG(LB, gB, 0, 0, t + 2); }
    BAR(); MFQ(4, 0, b0); BAR();

    if (!lastit) { STG(LB, gB, 0, 1, t + 2); VMCNT(4); }
    else         { VMCNT(0); }
    BAR(); MFQ(4, 2, b1); BAR();

#pragma unroll
    for (int i = 0; i < 4; i++) {
      a[i][0] = *(const f16x8*)(LA + 16384 + (wm + i * 16 + fr) * 64 + cA0);
      a[i][1] = *(const f16x8*)(LA + 16384 + (wm + i * 16 + fr) * 64 + cA1);
    }
#pragma unroll
    for (int j = 0; j < 2; j++) {
      b0[j][0] = *(const f16x8*)(LB + 16384 + (wn + j * 16 + fr) * 64 + cA0);
      b0[j][1] = *(const f16x8*)(LB + 16384 + (wn + j * 16 + fr) * 64 + cA1);
    }
    if (!lastit) { STG(LA, gA, 0, 0, t + 2); }
    BAR(); MFQ(0, 0, b0); BAR();

#pragma unroll
    for (int j = 0; j < 2; j++) {
      b1[j][0] = *(const f16x8*)(LB + 16384 + (wn + 32 + j * 16 + fr) * 64 + cA0);
      b1[j][1] = *(const f16x8*)(LB + 16384 + (wn + 32 + j * 16 + fr) * 64 + cA1);
    }
    if (!lastit) { STG(LA, gA, 0, 1, t + 2); }
    BAR(); MFQ(0, 2, b1); BAR();

#pragma unroll
    for (int i = 0; i < 4; i++) {
      a[i][0] = *(const f16x8*)(LA + 16384 + (wm + 64 + i * 16 + fr) * 64 + cA0);
      a[i][1] = *(const f16x8*)(LA + 16384 + (wm + 64 + i * 16 + fr) * 64 + cA1);
    }
    if (!lastit) { STG(LB, gB, 1, 0, t + 3); }
    BAR(); MFQ(4, 0, b0); BAR();

    if (!lastit) { STG(LB, gB, 1, 1, t + 3); VMCNT(4); }
    BAR(); MFQ(4, 2, b1); BAR();
  }

#pragma unroll
  for (int i = 0; i < 8; i++) {
    const int row = m0 + wm + i * 16 + fq * 4;
#pragma unroll
    for (int j = 0; j < 4; j++) {
      const int col = n0 + wn + j * 16 + fr;
      const float bv = bias[col];
#pragma unroll
      for (int q = 0; q < 4; q++)
        C[(size_t)(row + q) * NQ + col] = (f16)(acc[i][j][q] + bv);
    }
  }
}

// ---------------- 128^2 GEMM (proj) ----------------
template<int OUT_F32>
__global__ __launch_bounds__(256) void gemm_bt(const f16* __restrict__ A,
                                               const f16* __restrict__ B,
                                               const float* __restrict__ bias,
                                               void* __restrict__ C,
                                               int M, int N, int K) {
  __shared__ __align__(16) f16 As[128 * 32];
  __shared__ __align__(16) f16 Bs[128 * 32];
  const int tid = threadIdx.x;
  const int w = tid >> 6, l = tid & 63;
  const int m0 = blockIdx.y * 128, n0 = blockIdx.x * 128;
  const int wm = (w >> 1) * 64, wn = (w & 1) * 64;

  const int c0 = w * 64 + l;
  const int c1 = (4 + w) * 64 + l;
  const size_t a0 = (size_t)(m0 + (c0 >> 2)) * K + (c0 & 3) * 8;
  const size_t a1 = (size_t)(m0 + (c1 >> 2)) * K + (c1 & 3) * 8;
  const size_t b0 = (size_t)(n0 + (c0 >> 2)) * K + (c0 & 3) * 8;
  const size_t b1 = (size_t)(n0 + (c1 >> 2)) * K + (c1 & 3) * 8;

  f32x4 acc[4][4] = {};
  const int fr = l & 15, fg = (l >> 4) * 8;

  for (int k0 = 0; k0 < K; k0 += 32) {
    if (k0) __syncthreads();
    gload16(A + a0 + k0, As + w * 512);
    gload16(A + a1 + k0, As + (4 + w) * 512);
    gload16(B + b0 + k0, Bs + w * 512);
    gload16(B + b1 + k0, Bs + (4 + w) * 512);
    __syncthreads();
    f16x8 af[4], bf[4];
#pragma unroll
    for (int i = 0; i < 4; i++)
      af[i] = *(const f16x8*)(As + (wm + i * 16 + fr) * 32 + fg);
#pragma unroll
    for (int j = 0; j < 4; j++)
      bf[j] = *(const f16x8*)(Bs + (wn + j * 16 + fr) * 32 + fg);
#pragma unroll
    for (int i = 0; i < 4; i++)
#pragma unroll
      for (int j = 0; j < 4; j++)
        acc[i][j] = __builtin_amdgcn_mfma_f32_16x16x32_f16(af[i], bf[j], acc[i][j], 0, 0, 0);
  }

  const int q4 = (l >> 4) * 4;
#pragma unroll
  for (int i = 0; i < 4; i++) {
    const int row = m0 + wm + i * 16 + q4;
#pragma unroll
    for (int j = 0; j < 4; j++) {
      const int col = n0 + wn + j * 16 + fr;
      const float bv = bias[col];
#pragma unroll
      for (int q = 0; q < 4; q++) {
        float v = acc[i][j][q] + bv;
        if (OUT_F32) ((float*)C)[(size_t)(row + q) * N + col] = v;
        else         ((f16*)C)[(size_t)(row + q) * N + col] = (f16)v;
      }
    }
  }
}

// ---------------- RoPE ----------------
__global__ __launch_bounds__(256) void rope_kernel(const f16* __restrict__ qkvb,
                                                   const float* __restrict__ rpe,
                                                   f16* __restrict__ qh,
                                                   f16* __restrict__ kh) {
  const float SCLT = 0.1118033988749895f * 1.4426950408889634f;
  int t = blockIdx.x * 256 + threadIdx.x;
  if (t >= SEQ * NH * 40) return;
  const int d = t % 40;
  const int h = (t / 40) % NH;
  const int s = t / (40 * NH);
  const float f = rpe[s * 40 + d];
  float sn, cs;
  __sincosf(f, &sn, &cs);
  const size_t base = (size_t)s * (3 * HIDN) + h * HD;
  const float q0 = (float)qkvb[base + d];
  const float q1 = (float)qkvb[base + 40 + d];
  const float k0 = (float)qkvb[base + HIDN + d];
  const float k1 = (float)qkvb[base + HIDN + 40 + d];
  const size_t ob = ((size_t)h * SEQ + s) * DP;
  qh[ob + d]      = (f16)((q0 * cs - q1 * sn) * SCLT);
  qh[ob + 40 + d] = (f16)((q1 * cs + q0 * sn) * SCLT);
  kh[ob + d]      = (f16)(k0 * cs - k1 * sn);
  kh[ob + 40 + d] = (f16)(k1 * cs + k0 * sn);
  if (d < DP - HD) { qh[ob + HD + d] = (f16)0.f; kh[ob + HD + d] = (f16)0.f; }
}

// ---------------- V transpose ----------------
__global__ __launch_bounds__(256) void vtrans_kernel(const f16* __restrict__ qkvb,
                                                     f16* __restrict__ vt) {
  __shared__ f16 tile[HD][65];
  const int h = blockIdx.y;
  const int s0 = blockIdx.x * 64;
  for (int idx = threadIdx.x; idx < 64 * HD; idx += 256) {
    const int sr = idx / HD, d = idx % HD;
    tile[d][sr] = qkvb[(size_t)(s0 + sr) * (3 * HIDN) + 2 * HIDN + h * HD + d];
  }
  __syncthreads();
  for (int idx = threadIdx.x; idx < HD * 64; idx += 256) {
    const int d = idx >> 6, sc = idx & 63;
    vt[((size_t)h * HD + d) * SEQ + s0 + sc] = tile[d][sc];
  }
}

// ---------------- Flash attention, split-KV: 8 waves, groups of 4 handle
// even/odd kv-32 tiles with private online-softmax state; merged at end.
__global__ __launch_bounds__(512, 4) void attn_kernel(const f16* __restrict__ qh,
                                                      const f16* __restrict__ kh,
                                                      const f16* __restrict__ vt,
                                                      const int* __restrict__ cu,
                                                      f16* __restrict__ ao) {
  __shared__ __align__(16) f16 smem[29952];          // 59904 B
  f16* Ks = smem;                                     // [2][32*KROWS]
  f16* Vs = smem + 2 * 32 * KROWS;                    // [2][80*VROWS]
  f16* Ps = Vs + 2 * 80 * VROWS;                      // [8][32*PROWS]

  const int tid = threadIdx.x, w = tid >> 6, l = tid & 63;
  const int grp = w >> 2, wq = w & 3;
  const int h = blockIdx.y;
  const int row0 = blockIdx.x * 128;
  int seg = 0;
  while (cu[seg + 1] <= row0) seg++;
  const int kvb = cu[seg], kve = cu[seg + 1];

  const int fr = l & 15, fg = (l >> 4) * 8;

  const f16* qb = qh + ((size_t)h * SEQ + row0 + wq * 32 + fr) * DP + fg;
  f16x8 aq0[3], aq1[3];
#pragma unroll
  for (int kk = 0; kk < 3; kk++) {
    aq0[kk] = *(const f16x8*)(qb + kk * 32);
    aq1[kk] = *(const f16x8*)(qb + 16 * DP + kk * 32);
  }

  // staging geometry: K = 768 chunks (2 tiles x 32 x 12), V = 640 (2 x 80 x 4)
  const int kt0 = tid / 384, kr0 = (tid % 384) / 12, kg0 = tid % 12;
  const int kr1 = (tid + 128) / 12, kg1 = (tid + 128) % 12;    // chunk tid+512 -> tile 1
  const int vt0 = tid / 320, vr0 = (tid % 320) / 4, vg = tid & 3;
  const int vr1 = (tid + 192) >> 2;                            // chunk tid+512 -> tile 1
  const f16* kpA = kh + ((size_t)h * SEQ + kvb + kt0 * 32 + kr0) * DP + kg0 * 8;
  const f16* kpB = kh + ((size_t)h * SEQ + kvb + 32 + kr1) * DP + kg1 * 8;
  const f16* vpA = vt + ((size_t)h * HD + vr0) * SEQ + kvb + vt0 * 32 + vg * 8;
  const f16* vpB = vt + ((size_t)h * HD + vr1) * SEQ + kvb + 32 + vg * 8;
  f16* klA = Ks + kt0 * (32 * KROWS) + kr0 * KROWS + kg0 * 8;
  f16* klB = Ks + (32 * KROWS) + kr1 * KROWS + kg1 * 8;
  f16* vlA = Vs + vt0 * (80 * VROWS) + vr0 * VROWS + vg * 8;
  f16* vlB = Vs + (80 * VROWS) + vr1 * VROWS + vg * 8;

  uint4 rka, rkb, rva, rvb;
  rka = *(const uint4*)kpA;
  if (tid < 256) rkb = *(const uint4*)kpB;
  rva = *(const uint4*)vpA;
  if (tid < 128) rvb = *(const uint4*)vpB;

  float m = -1e30f;
  float ls0[4] = {0.f, 0.f, 0.f, 0.f}, ls1[4] = {0.f, 0.f, 0.f, 0.f};
  f32x4 o0[5] = {}, o1[5] = {};
  f16* pb = Ps + w * (32 * PROWS);
  const f16* myK = Ks + grp * (32 * KROWS);
  const f16* myV = Vs + grp * (80 * VROWS);

  for (int kv0 = kvb; kv0 < kve; kv0 += 64) {
    __syncthreads();
    *(uint4*)klA = rka;
    if (tid < 256) *(uint4*)klB = rkb;
    *(uint4*)vlA = rva;
    if (tid < 128) *(uint4*)vlB = rvb;
    __syncthreads();

    const int nxt = kv0 + 64 - kvb;
    if (kv0 + 64 < kve) {
      rka = *(const uint4*)(kpA + (size_t)nxt * DP);
      if (tid < 256) rkb = *(const uint4*)(kpB + (size_t)nxt * DP);
      rva = *(const uint4*)(vpA + nxt);
      if (tid < 128) rvb = *(const uint4*)(vpB + nxt);
    }

    if (kv0 + grp * 32 < kve) {   // this group's tile exists
      f32x4 sA0 = {0.f,0.f,0.f,0.f}, sA1 = {0.f,0.f,0.f,0.f};
      f32x4 sB0 = {0.f,0.f,0.f,0.f}, sB1 = {0.f,0.f,0.f,0.f};
      __builtin_amdgcn_s_setprio(1);
#pragma unroll
      for (int kk = 0; kk < 3; kk++) {
        f16x8 b0 = *(const f16x8*)(myK + fr * KROWS + kk * 32 + fg);
        f16x8 b1 = *(const f16x8*)(myK + (16 + fr) * KROWS + kk * 32 + fg);
        sA0 = __builtin_amdgcn_mfma_f32_16x16x32_f16(aq0[kk], b0, sA0, 0, 0, 0);
        sA1 = __builtin_amdgcn_mfma_f32_16x16x32_f16(aq0[kk], b1, sA1, 0, 0, 0);
        sB0 = __builtin_amdgcn_mfma_f32_16x16x32_f16(aq1[kk], b0, sB0, 0, 0, 0);
        sB1 = __builtin_amdgcn_mfma_f32_16x16x32_f16(aq1[kk], b1, sB1, 0, 0, 0);
      }
      __builtin_amdgcn_s_setprio(0);

      float tmax = sA0[0];
#pragma unroll
      for (int j = 0; j < 4; j++) {
        tmax = fmaxf(tmax, fmaxf(sA0[j], sA1[j]));
        tmax = fmaxf(tmax, fmaxf(sB0[j], sB1[j]));
      }
      tmax = fmaxf(tmax, __shfl_xor(tmax, 1));
      tmax = fmaxf(tmax, __shfl_xor(tmax, 2));
      tmax = fmaxf(tmax, __shfl_xor(tmax, 4));
      tmax = fmaxf(tmax, __shfl_xor(tmax, 8));
      tmax = fmaxf(tmax, __shfl_xor(tmax, 16));
      tmax = fmaxf(tmax, __shfl_xor(tmax, 32));

      if (tmax > m + 8.f) {
        const float aa = exp2f(m - tmax);
        m = tmax;
#pragma unroll
        for (int j = 0; j < 4; j++) { ls0[j] *= aa; ls1[j] *= aa; }
#pragma unroll
        for (int dt = 0; dt < 5; dt++)
#pragma unroll
          for (int j = 0; j < 4; j++) { o0[dt][j] *= aa; o1[dt][j] *= aa; }
      }

#pragma unroll
      for (int j = 0; j < 4; j++) {
        const float pA0 = exp2f(sA0[j] - m), pA1 = exp2f(sA1[j] - m);
        const float pB0 = exp2f(sB0[j] - m), pB1 = exp2f(sB1[j] - m);
        ls0[j] += pA0 + pA1;
        ls1[j] += pB0 + pB1;
        const int pr = (l >> 4) * 4 + j;
        pb[pr * PROWS + fr]             = (f16)pA0;
        pb[pr * PROWS + 16 + fr]        = (f16)pA1;
        pb[(16 + pr) * PROWS + fr]      = (f16)pB0;
        pb[(16 + pr) * PROWS + 16 + fr] = (f16)pB1;
      }

      f16x8 paA = *(const f16x8*)(pb + fr * PROWS + fg);
      f16x8 paB = *(const f16x8*)(pb + (16 + fr) * PROWS + fg);
      __builtin_amdgcn_s_setprio(1);
#pragma unroll
      for (int dt = 0; dt < 5; dt++) {
        f16x8 bv = *(const f16x8*)(myV + (dt * 16 + fr) * VROWS + fg);
        o0[dt] = __builtin_amdgcn_mfma_f32_16x16x32_f16(paA, bv, o0[dt], 0, 0, 0);
        o1[dt] = __builtin_amdgcn_mfma_f32_16x16x32_f16(paB, bv, o1[dt], 0, 0, 0);
      }
      __builtin_amdgcn_s_setprio(0);
    }
  }

  // per-row sums (full row sum replicated in lanes after fr-bit reduce)
#pragma unroll
  for (int j = 0; j < 4; j++) {
    float sa = ls0[j], sb = ls1[j];
    sa += __shfl_xor(sa, 1); sb += __shfl_xor(sb, 1);
    sa += __shfl_xor(sa, 2); sb += __shfl_xor(sb, 2);
    sa += __shfl_xor(sa, 4); sb += __shfl_xor(sb, 4);
    sa += __shfl_xor(sa, 8); sb += __shfl_xor(sb, 8);
    ls0[j] = sa; ls1[j] = sb;
  }

  // merge the two groups' partial states (waves w and w+4 share q-rows)
  __syncthreads();
  float* mb = (float*)smem;                    // reuse all of LDS; 4*64*51*4B = 52224 B
  if (grp == 1) {
    float* dst = mb + (wq * 64 + l) * 51;
#pragma unroll
    for (int j = 0; j < 4; j++) { dst[j] = ls0[j]; dst[4 + j] = ls1[j]; }
#pragma unroll
    for (int dt = 0; dt < 5; dt++)
#pragma unroll
      for (int j = 0; j < 4; j++) {
        dst[8 + dt * 4 + j]  = o0[dt][j];
        dst[28 + dt * 4 + j] = o1[dt][j];
      }
    dst[48] = m;
  }
  __syncthreads();
  if (grp == 0) {
    const float* src = mb + (wq * 64 + l) * 51;
    const float mB = src[48];
    const float M = fmaxf(m, mB);
    const float aA = exp2f(m - M), aB = exp2f(mB - M);
    float inv0[4], inv1[4];
#pragma unroll
    for (int j = 0; j < 4; j++) {
      inv0[j] = 1.0f / (ls0[j] * aA + src[j] * aB);
      inv1[j] = 1.0f / (ls1[j] * aA + src[4 + j] * aB);
    }
    const int orow = row0 + wq * 32 + (l >> 4) * 4;
#pragma unroll
    for (int dt = 0; dt < 5; dt++)
#pragma unroll
      for (int j = 0; j < 4; j++) {
        ao[(size_t)(orow + j) * HIDN + h * HD + dt * 16 + fr] =
            (f16)((o0[dt][j] * aA + src[8 + dt * 4 + j] * aB) * inv0[j]);
        ao[(size_t)(orow + 16 + j) * HIDN + h * HD + dt * 16 + fr] =
            (f16)((o1[dt][j] * aA + src[28 + dt * 4 + j] * aB) * inv1[j]);
      }
  }
}

extern "C" void kernel_launch(void* const* d_in, const int* in_sizes, int n_in,
                              void* d_out, int out_size, void* d_ws, size_t ws_size,
                              hipStream_t stream) {
  const float* x      = (const float*)d_in[0];
  const int*   cu     = (const int*)d_in[1];
  const float* rpe    = (const float*)d_in[2];
  const float* qkv_w  = (const float*)d_in[3];
  const float* qkv_b  = (const float*)d_in[4];
  const float* proj_w = (const float*)d_in[5];
  const float* proj_b = (const float*)d_in[6];

  char* ws = (char*)d_ws;
  f16* xb    = (f16*)(ws);              // [4096][1280]
  f16* wqkv  = (f16*)(ws + 10485760);   // [3840][1280]
  f16* wproj = (f16*)(ws + 20316160);   // [1280][1280]
  f16* qkvb  = (f16*)(ws + 23592960);   // [4096][3840]
  f16* qh    = (f16*)(ws + 55050240);   // [16][4096][96]
  f16* kh    = (f16*)(ws + 67633152);   // [16][4096][96]
  f16* vt    = (f16*)(ws + 80216064);   // [16][80][4096]
  f16* ao    = xb;

  cvt_kernel<<<2560, 256, 0, stream>>>(x, xb, SEQ * HIDN);
  cvt_kernel<<<2400, 256, 0, stream>>>(qkv_w, wqkv, 3 * HIDN * HIDN);
  cvt_kernel<<<800, 256, 0, stream>>>(proj_w, wproj, HIDN * HIDN);

  qkv_gemm8<<<240, 512, 0, stream>>>(xb, wqkv, qkv_b, qkvb);

  rope_kernel<<<(SEQ * NH * 40) / 256, 256, 0, stream>>>(qkvb, rpe, qh, kh);
  vtrans_kernel<<<dim3(SEQ / 64, NH), 256, 0, stream>>>(qkvb, vt);

  attn_kernel<<<dim3(SEQ / 128, NH), 512, 0, stream>>>(qh, kh, vt, cu, ao);

  gemm_bt<1><<<dim3(HIDN / 128, SEQ / 128), 256, 0, stream>>>(
      ao, wproj, proj_b, d_out, SEQ, HIDN, HIDN);
}

// Round 5
// 167.336 us; speedup vs baseline: 1.0543x; 1.0543x over previous
//
#include <hip/hip_runtime.h>

typedef _Float16 f16;
typedef __attribute__((ext_vector_type(8))) _Float16 f16x8;
typedef __attribute__((ext_vector_type(4))) float f32x4;

#define SEQ   4096
#define NH    16
#define HD    80
#define HIDN  1280
#define DP    96
#define KROWS 104
#define VROWS 56

// 8-phase GEMM constants (QKV: M=4096, N=3840, K=1280)
#define KQ   1280
#define NQ   3840
#define NIT  10      // K / 128

__device__ __forceinline__ void gload16(const void* g, void* l) {
  __builtin_amdgcn_global_load_lds(
      (const __attribute__((address_space(1))) unsigned int*)g,
      (__attribute__((address_space(3))) unsigned int*)l, 16, 0, 0);
}

#define BAR() __builtin_amdgcn_s_barrier()
#define VMCNT(n) do { asm volatile("s_waitcnt vmcnt(" #n ")" ::: "memory"); \
                      __builtin_amdgcn_sched_barrier(0); } while (0)
#define STG(Lb, g, buf, h, kt)                                                  \
  do {                                                                          \
    gload16((g) + (size_t)((h) * 128) * KQ + (kt) * 64,                         \
            (Lb) + (buf) * 16384 + ((h) * 128) * 64 + w * 512);                 \
    gload16((g) + (size_t)((h) * 128 + 64) * KQ + (kt) * 64,                    \
            (Lb) + (buf) * 16384 + ((h) * 128 + 64) * 64 + w * 512);            \
  } while (0)
#define MFQ(IOFF, JOFF, BB)                                                     \
  do {                                                                          \
    __builtin_amdgcn_s_setprio(1);                                              \
    _Pragma("unroll")                                                           \
    for (int i_ = 0; i_ < 4; i_++)                                              \
      _Pragma("unroll")                                                         \
      for (int j_ = 0; j_ < 2; j_++)                                            \
        _Pragma("unroll")                                                       \
        for (int s_ = 0; s_ < 2; s_++)                                          \
          acc[i_ + IOFF][j_ + JOFF] = __builtin_amdgcn_mfma_f32_16x16x32_f16(   \
              a[i_][s_], BB[j_][s_], acc[i_ + IOFF][j_ + JOFF], 0, 0, 0);       \
    __builtin_amdgcn_s_setprio(0);                                              \
  } while (0)

// ---------------- f32 -> f16 convert (n % 8 == 0) ----------------
__global__ __launch_bounds__(256) void cvt_kernel(const float* __restrict__ s,
                                                  f16* __restrict__ d, int n) {
  int base = (blockIdx.x * 256 + threadIdx.x) * 8;
  if (base >= n) return;
  f32x4 v0 = *(const f32x4*)(s + base);
  f32x4 v1 = *(const f32x4*)(s + base + 4);
  f16x8 o;
#pragma unroll
  for (int j = 0; j < 4; j++) { o[j] = (f16)v0[j]; o[4 + j] = (f16)v1[j]; }
  *(f16x8*)(d + base) = o;
}

// ---------------- 8-phase 256^2 GEMM: C[4096][3840] = A * B^T + bias (f16 out) ----
__global__ __launch_bounds__(512, 2) void qkv_gemm8(const f16* __restrict__ A,
                                                    const f16* __restrict__ B,
                                                    const float* __restrict__ bias,
                                                    f16* __restrict__ C) {
  __shared__ __align__(16) f16 LA[2 * 16384];
  __shared__ __align__(16) f16 LB[2 * 16384];
  const int tid = threadIdx.x, w = tid >> 6, l = tid & 63;
  const int bid = (blockIdx.x & 7) * 30 + (blockIdx.x >> 3);
  const int bx = bid % 15, by = bid / 15;
  const int m0 = by * 256, n0 = bx * 256;
  const int wm = (w >> 2) * 128, wn = (w & 3) * 64;
  const int fr = l & 15, fq = l >> 4;
  const int rx = fr & 7;
  const int cA0 = (fq ^ rx) * 8;
  const int cA1 = ((4 + fq) ^ rx) * 8;

  const int srow = w * 8 + (l >> 3);
  const int scol = ((l & 7) ^ (l >> 3)) * 8;
  const f16* gA = A + (size_t)(m0 + srow) * KQ + scol;
  const f16* gB = B + (size_t)(n0 + srow) * KQ + scol;

  f32x4 acc[8][4] = {};
  f16x8 a[4][2], b0[2][2], b1[2][2];

  STG(LA, gA, 0, 0, 0); STG(LA, gA, 0, 1, 0);
  STG(LB, gB, 0, 0, 0); STG(LB, gB, 0, 1, 0);
  STG(LB, gB, 1, 0, 1); STG(LB, gB, 1, 1, 1);
  VMCNT(4);
  BAR();

  for (int it = 0; it < NIT; ++it) {
    const int t = 2 * it;
    const bool lastit = (it == NIT - 1);

#pragma unroll
    for (int i = 0; i < 4; i++) {
      a[i][0] = *(const f16x8*)(LA + (wm + i * 16 + fr) * 64 + cA0);
      a[i][1] = *(const f16x8*)(LA + (wm + i * 16 + fr) * 64 + cA1);
    }
#pragma unroll
    for (int j = 0; j < 2; j++) {
      b0[j][0] = *(const f16x8*)(LB + (wn + j * 16 + fr) * 64 + cA0);
      b0[j][1] = *(const f16x8*)(LB + (wn + j * 16 + fr) * 64 + cA1);
    }
    STG(LA, gA, 1, 0, t + 1);
    BAR(); MFQ(0, 0, b0); BAR();

#pragma unroll
    for (int j = 0; j < 2; j++) {
      b1[j][0] = *(const f16x8*)(LB + (wn + 32 + j * 16 + fr) * 64 + cA0);
      b1[j][1] = *(const f16x8*)(LB + (wn + 32 + j * 16 + fr) * 64 + cA1);
    }
    STG(LA, gA, 1, 1, t + 1);
    BAR(); MFQ(0, 2, b1); BAR();

#pragma unroll
    for (int i = 0; i < 4; i++) {
      a[i][0] = *(const f16x8*)(LA + (wm + 64 + i * 16 + fr) * 64 + cA0);
      a[i][1] = *(const f16x8*)(LA + (wm + 64 + i * 16 + fr) * 64 + cA1);
    }
    if (!lastit) { STG(LB, gB, 0, 0, t + 2); }
    BAR(); MFQ(4, 0, b0); BAR();

    if (!lastit) { STG(LB, gB, 0, 1, t + 2); VMCNT(4); }
    else         { VMCNT(0); }
    BAR(); MFQ(4, 2, b1); BAR();

#pragma unroll
    for (int i = 0; i < 4; i++) {
      a[i][0] = *(const f16x8*)(LA + 16384 + (wm + i * 16 + fr) * 64 + cA0);
      a[i][1] = *(const f16x8*)(LA + 16384 + (wm + i * 16 + fr) * 64 + cA1);
    }
#pragma unroll
    for (int j = 0; j < 2; j++) {
      b0[j][0] = *(const f16x8*)(LB + 16384 + (wn + j * 16 + fr) * 64 + cA0);
      b0[j][1] = *(const f16x8*)(LB + 16384 + (wn + j * 16 + fr) * 64 + cA1);
    }
    if (!lastit) { STG(LA, gA, 0, 0, t + 2); }
    BAR(); MFQ(0, 0, b0); BAR();

#pragma unroll
    for (int j = 0; j < 2; j++) {
      b1[j][0] = *(const f16x8*)(LB + 16384 + (wn + 32 + j * 16 + fr) * 64 + cA0);
      b1[j][1] = *(const f16x8*)(LB + 16384 + (wn + 32 + j * 16 + fr) * 64 + cA1);
    }
    if (!lastit) { STG(LA, gA, 0, 1, t + 2); }
    BAR(); MFQ(0, 2, b1); BAR();

#pragma unroll
    for (int i = 0; i < 4; i++) {
      a[i][0] = *(const f16x8*)(LA + 16384 + (wm + 64 + i * 16 + fr) * 64 + cA0);
      a[i][1] = *(const f16x8*)(LA + 16384 + (wm + 64 + i * 16 + fr) * 64 + cA1);
    }
    if (!lastit) { STG(LB, gB, 1, 0, t + 3); }
    BAR(); MFQ(4, 0, b0); BAR();

    if (!lastit) { STG(LB, gB, 1, 1, t + 3); VMCNT(4); }
    BAR(); MFQ(4, 2, b1); BAR();
  }

#pragma unroll
  for (int i = 0; i < 8; i++) {
    const int row = m0 + wm + i * 16 + fq * 4;
#pragma unroll
    for (int j = 0; j < 4; j++) {
      const int col = n0 + wn + j * 16 + fr;
      const float bv = bias[col];
#pragma unroll
      for (int q = 0; q < 4; q++)
        C[(size_t)(row + q) * NQ + col] = (f16)(acc[i][j][q] + bv);
    }
  }
}

// ---------------- 128^2 GEMM (proj) ----------------
template<int OUT_F32>
__global__ __launch_bounds__(256) void gemm_bt(const f16* __restrict__ A,
                                               const f16* __restrict__ B,
                                               const float* __restrict__ bias,
                                               void* __restrict__ C,
                                               int M, int N, int K) {
  __shared__ __align__(16) f16 As[128 * 32];
  __shared__ __align__(16) f16 Bs[128 * 32];
  const int tid = threadIdx.x;
  const int w = tid >> 6, l = tid & 63;
  const int m0 = blockIdx.y * 128, n0 = blockIdx.x * 128;
  const int wm = (w >> 1) * 64, wn = (w & 1) * 64;

  const int c0 = w * 64 + l;
  const int c1 = (4 + w) * 64 + l;
  const size_t a0 = (size_t)(m0 + (c0 >> 2)) * K + (c0 & 3) * 8;
  const size_t a1 = (size_t)(m0 + (c1 >> 2)) * K + (c1 & 3) * 8;
  const size_t b0 = (size_t)(n0 + (c0 >> 2)) * K + (c0 & 3) * 8;
  const size_t b1 = (size_t)(n0 + (c1 >> 2)) * K + (c1 & 3) * 8;

  f32x4 acc[4][4] = {};
  const int fr = l & 15, fg = (l >> 4) * 8;

  for (int k0 = 0; k0 < K; k0 += 32) {
    if (k0) __syncthreads();
    gload16(A + a0 + k0, As + w * 512);
    gload16(A + a1 + k0, As + (4 + w) * 512);
    gload16(B + b0 + k0, Bs + w * 512);
    gload16(B + b1 + k0, Bs + (4 + w) * 512);
    __syncthreads();
    f16x8 af[4], bf[4];
#pragma unroll
    for (int i = 0; i < 4; i++)
      af[i] = *(const f16x8*)(As + (wm + i * 16 + fr) * 32 + fg);
#pragma unroll
    for (int j = 0; j < 4; j++)
      bf[j] = *(const f16x8*)(Bs + (wn + j * 16 + fr) * 32 + fg);
#pragma unroll
    for (int i = 0; i < 4; i++)
#pragma unroll
      for (int j = 0; j < 4; j++)
        acc[i][j] = __builtin_amdgcn_mfma_f32_16x16x32_f16(af[i], bf[j], acc[i][j], 0, 0, 0);
  }

  const int q4 = (l >> 4) * 4;
#pragma unroll
  for (int i = 0; i < 4; i++) {
    const int row = m0 + wm + i * 16 + q4;
#pragma unroll
    for (int j = 0; j < 4; j++) {
      const int col = n0 + wn + j * 16 + fr;
      const float bv = bias[col];
#pragma unroll
      for (int q = 0; q < 4; q++) {
        float v = acc[i][j][q] + bv;
        if (OUT_F32) ((float*)C)[(size_t)(row + q) * N + col] = v;
        else         ((f16*)C)[(size_t)(row + q) * N + col] = (f16)v;
      }
    }
  }
}

// ---------------- RoPE ----------------
__global__ __launch_bounds__(256) void rope_kernel(const f16* __restrict__ qkvb,
                                                   const float* __restrict__ rpe,
                                                   f16* __restrict__ qh,
                                                   f16* __restrict__ kh) {
  const float SCLT = 0.1118033988749895f * 1.4426950408889634f;
  int t = blockIdx.x * 256 + threadIdx.x;
  if (t >= SEQ * NH * 40) return;
  const int d = t % 40;
  const int h = (t / 40) % NH;
  const int s = t / (40 * NH);
  const float f = rpe[s * 40 + d];
  float sn, cs;
  __sincosf(f, &sn, &cs);
  const size_t base = (size_t)s * (3 * HIDN) + h * HD;
  const float q0 = (float)qkvb[base + d];
  const float q1 = (float)qkvb[base + 40 + d];
  const float k0 = (float)qkvb[base + HIDN + d];
  const float k1 = (float)qkvb[base + HIDN + 40 + d];
  const size_t ob = ((size_t)h * SEQ + s) * DP;
  qh[ob + d]      = (f16)((q0 * cs - q1 * sn) * SCLT);
  qh[ob + 40 + d] = (f16)((q1 * cs + q0 * sn) * SCLT);
  kh[ob + d]      = (f16)(k0 * cs - k1 * sn);
  kh[ob + 40 + d] = (f16)(k1 * cs + k0 * sn);
  if (d < DP - HD) { qh[ob + HD + d] = (f16)0.f; kh[ob + HD + d] = (f16)0.f; }
}

// ---------------- V transpose: vt[h][d][slot], kv-permuted within 32-blocks ----
// slot s (within 32): g=s>>3, j=s&7 -> actual kv = j<4 ? 4g+j : 16+4g+(j-4).
// This matches the MFMA k-slot layout so P (from swapped QK^T) feeds PV directly.
__global__ __launch_bounds__(256) void vtrans_kernel(const f16* __restrict__ qkvb,
                                                     f16* __restrict__ vt) {
  __shared__ f16 tile[HD][65];
  const int h = blockIdx.y;
  const int s0 = blockIdx.x * 64;
  for (int idx = threadIdx.x; idx < 64 * HD; idx += 256) {
    const int sr = idx / HD, d = idx % HD;
    tile[d][sr] = qkvb[(size_t)(s0 + sr) * (3 * HIDN) + 2 * HIDN + h * HD + d];
  }
  __syncthreads();
  for (int idx = threadIdx.x; idx < HD * 64; idx += 256) {
    const int d = idx >> 6, sc = idx & 63;
    const int b = sc >> 5, s = sc & 31, g = s >> 3, j = s & 7;
    const int act = b * 32 + ((j < 4) ? (4 * g + j) : (16 + 4 * g + (j - 4)));
    vt[((size_t)h * HD + d) * SEQ + s0 + sc] = tile[d][act];
  }
}

// ---------------- Flash attention: swapped QK^T, P in registers ----------------
// 8 waves: groups of 4 handle even/odd kv-32 tiles; 32 q-rows per wave.
// S^T = mfma(K,Q): lane holds q=l&15, kv=4g+reg (+16 per kv-subtile) -> exp'd
// values pack directly into the PV A-fragment (V columns pre-permuted in vtrans).
__global__ __launch_bounds__(512, 4) void attn_kernel(const f16* __restrict__ qh,
                                                      const f16* __restrict__ kh,
                                                      const f16* __restrict__ vt,
                                                      const int* __restrict__ cu,
                                                      f16* __restrict__ ao) {
  __shared__ __align__(16) f16 smem[15616];           // 31,232 B
  f16* Ks = smem;                                      // [2][32*KROWS]
  f16* Vs = smem + 2 * 32 * KROWS;                     // [2][80*VROWS]

  const int tid = threadIdx.x, w = tid >> 6, l = tid & 63;
  const int grp = w >> 2, wq = w & 3;
  const int h = blockIdx.y;
  const int row0 = blockIdx.x * 128;
  int seg = 0;
  while (cu[seg + 1] <= row0) seg++;
  const int kvb = cu[seg], kve = cu[seg + 1];

  const int fr = l & 15, fg = (l >> 4) * 8;

  // Q fragments (now the B-operand of swapped QK^T)
  const f16* qb = qh + ((size_t)h * SEQ + row0 + wq * 32 + fr) * DP + fg;
  f16x8 aq0[3], aq1[3];
#pragma unroll
  for (int kk = 0; kk < 3; kk++) {
    aq0[kk] = *(const f16x8*)(qb + kk * 32);
    aq1[kk] = *(const f16x8*)(qb + 16 * DP + kk * 32);
  }

  // staging geometry: K = 768 chunks (2 tiles x 32 x 12), V = 640 (2 x 80 x 4)
  const int kt0 = tid / 384, kr0 = (tid % 384) / 12, kg0 = tid % 12;
  const int kr1 = (tid + 128) / 12, kg1 = (tid + 128) % 12;
  const int vt0 = tid / 320, vr0 = (tid % 320) / 4, vg = tid & 3;
  const int vr1 = (tid + 192) >> 2;
  const f16* kpA = kh + ((size_t)h * SEQ + kvb + kt0 * 32 + kr0) * DP + kg0 * 8;
  const f16* kpB = kh + ((size_t)h * SEQ + kvb + 32 + kr1) * DP + kg1 * 8;
  const f16* vpA = vt + ((size_t)h * HD + vr0) * SEQ + kvb + vt0 * 32 + vg * 8;
  const f16* vpB = vt + ((size_t)h * HD + vr1) * SEQ + kvb + 32 + vg * 8;
  f16* klA = Ks + kt0 * (32 * KROWS) + kr0 * KROWS + kg0 * 8;
  f16* klB = Ks + (32 * KROWS) + kr1 * KROWS + kg1 * 8;
  f16* vlA = Vs + vt0 * (80 * VROWS) + vr0 * VROWS + vg * 8;
  f16* vlB = Vs + (80 * VROWS) + vr1 * VROWS + vg * 8;

  uint4 rka, rkb, rva, rvb;
  rka = *(const uint4*)kpA;
  if (tid < 256) rkb = *(const uint4*)kpB;
  rva = *(const uint4*)vpA;
  if (tid < 128) rvb = *(const uint4*)vpB;

  float m = -1e30f;
  float ls0 = 0.f, ls1 = 0.f;         // per-lane partial row-sums (row = l&15)
  f32x4 o0[5] = {}, o1[5] = {};
  const f16* myK = Ks + grp * (32 * KROWS);
  const f16* myV = Vs + grp * (80 * VROWS);

  for (int kv0 = kvb; kv0 < kve; kv0 += 64) {
    __syncthreads();
    *(uint4*)klA = rka;
    if (tid < 256) *(uint4*)klB = rkb;
    *(uint4*)vlA = rva;
    if (tid < 128) *(uint4*)vlB = rvb;
    __syncthreads();

    const int nxt = kv0 + 64 - kvb;
    if (kv0 + 64 < kve) {
      rka = *(const uint4*)(kpA + (size_t)nxt * DP);
      if (tid < 256) rkb = *(const uint4*)(kpB + (size_t)nxt * DP);
      rva = *(const uint4*)(vpA + nxt);
      if (tid < 128) rvb = *(const uint4*)(vpB + nxt);
    }

    if (kv0 + grp * 32 < kve) {
      // swapped QK^T: S^T[kv][q] tiles; s{kvsub}{qhalf}
      f32x4 s00 = {0.f,0.f,0.f,0.f}, s10 = {0.f,0.f,0.f,0.f};
      f32x4 s01 = {0.f,0.f,0.f,0.f}, s11 = {0.f,0.f,0.f,0.f};
      __builtin_amdgcn_s_setprio(1);
#pragma unroll
      for (int kk = 0; kk < 3; kk++) {
        f16x8 k0 = *(const f16x8*)(myK + fr * KROWS + kk * 32 + fg);
        f16x8 k1 = *(const f16x8*)(myK + (16 + fr) * KROWS + kk * 32 + fg);
        s00 = __builtin_amdgcn_mfma_f32_16x16x32_f16(k0, aq0[kk], s00, 0, 0, 0);
        s10 = __builtin_amdgcn_mfma_f32_16x16x32_f16(k1, aq0[kk], s10, 0, 0, 0);
        s01 = __builtin_amdgcn_mfma_f32_16x16x32_f16(k0, aq1[kk], s01, 0, 0, 0);
        s11 = __builtin_amdgcn_mfma_f32_16x16x32_f16(k1, aq1[kk], s11, 0, 0, 0);
      }
      __builtin_amdgcn_s_setprio(0);

      // wave-uniform max (scores in log2 units; q pre-scaled)
      float tmax = s00[0];
#pragma unroll
      for (int j = 0; j < 4; j++) {
        tmax = fmaxf(tmax, fmaxf(s00[j], s10[j]));
        tmax = fmaxf(tmax, fmaxf(s01[j], s11[j]));
      }
      tmax = fmaxf(tmax, __shfl_xor(tmax, 1));
      tmax = fmaxf(tmax, __shfl_xor(tmax, 2));
      tmax = fmaxf(tmax, __shfl_xor(tmax, 4));
      tmax = fmaxf(tmax, __shfl_xor(tmax, 8));
      tmax = fmaxf(tmax, __shfl_xor(tmax, 16));
      tmax = fmaxf(tmax, __shfl_xor(tmax, 32));

      if (tmax > m + 8.f) {            // deferred rescale (T13)
        const float aa = exp2f(m - tmax);
        m = tmax;
        ls0 *= aa; ls1 *= aa;
#pragma unroll
        for (int dt = 0; dt < 5; dt++)
#pragma unroll
          for (int j = 0; j < 4; j++) { o0[dt][j] *= aa; o1[dt][j] *= aa; }
      }

      // P = exp2(S - m) packed straight into PV A-fragments (k-slot = perm order)
      f16x8 paA, paB;
#pragma unroll
      for (int r = 0; r < 4; r++) {
        const float e0 = exp2f(s00[r] - m);
        const float e1 = exp2f(s10[r] - m);
        const float e2 = exp2f(s01[r] - m);
        const float e3 = exp2f(s11[r] - m);
        ls0 += e0 + e1;
        ls1 += e2 + e3;
        paA[r] = (f16)e0; paA[4 + r] = (f16)e1;
        paB[r] = (f16)e2; paB[4 + r] = (f16)e3;
      }

      __builtin_amdgcn_s_setprio(1);
#pragma unroll
      for (int dt = 0; dt < 5; dt++) {
        f16x8 bv = *(const f16x8*)(myV + (dt * 16 + fr) * VROWS + fg);
        o0[dt] = __builtin_amdgcn_mfma_f32_16x16x32_f16(paA, bv, o0[dt], 0, 0, 0);
        o1[dt] = __builtin_amdgcn_mfma_f32_16x16x32_f16(paB, bv, o1[dt], 0, 0, 0);
      }
      __builtin_amdgcn_s_setprio(0);
    }
  }

  // complete row-sums: partials are spread across g = l>>4
  ls0 += __shfl_xor(ls0, 16); ls0 += __shfl_xor(ls0, 32);
  ls1 += __shfl_xor(ls1, 16); ls1 += __shfl_xor(ls1, 32);

  // two-phase group merge through LDS (fits in 31 KB)
  float* mb = (float*)smem;
  float aA = 1.f, aB = 0.f;
  __syncthreads();
  if (grp == 1) {                       // phase A: m, ls0, o0
    float* dst = mb + (wq * 64 + l) * 22;
    dst[0] = m; dst[1] = ls0;
#pragma unroll
    for (int dt = 0; dt < 5; dt++)
#pragma unroll
      for (int j = 0; j < 4; j++) dst[2 + dt * 4 + j] = o0[dt][j];
  }
  __syncthreads();
  if (grp == 0) {
    const float* src = mb + (wq * 64 + l) * 22;
    const float mB = src[0];
    const float M = fmaxf(m, mB);
    aA = exp2f(m - M); aB = exp2f(mB - M);
    ls0 = ls0 * aA + src[1] * aB;
#pragma unroll
    for (int dt = 0; dt < 5; dt++)
#pragma unroll
      for (int j = 0; j < 4; j++)
        o0[dt][j] = o0[dt][j] * aA + src[2 + dt * 4 + j] * aB;
  }
  __syncthreads();
  if (grp == 1) {                       // phase B: ls1, o1
    float* dst = mb + (wq * 64 + l) * 21;
    dst[0] = ls1;
#pragma unroll
    for (int dt = 0; dt < 5; dt++)
#pragma unroll
      for (int j = 0; j < 4; j++) dst[1 + dt * 4 + j] = o1[dt][j];
  }
  __syncthreads();
  if (grp == 0) {
    const float* src = mb + (wq * 64 + l) * 21;
    ls1 = ls1 * aA + src[0] * aB;
#pragma unroll
    for (int dt = 0; dt < 5; dt++)
#pragma unroll
      for (int j = 0; j < 4; j++)
        o1[dt][j] = o1[dt][j] * aA + src[1 + dt * 4 + j] * aB;

    // redistribute 1/rowsum (indexed by q=l&15) to o-rows (q'=4*(l>>4)+j)
    const float inv0 = 1.0f / ls0, inv1 = 1.0f / ls1;
    float iv0[4], iv1[4];
#pragma unroll
    for (int j = 0; j < 4; j++) {
      const int srcl = (l & 48) | ((l >> 4) * 4 + j);
      iv0[j] = __shfl(inv0, srcl);
      iv1[j] = __shfl(inv1, srcl);
    }
    const int orow = row0 + wq * 32 + (l >> 4) * 4;
#pragma unroll
    for (int dt = 0; dt < 5; dt++)
#pragma unroll
      for (int j = 0; j < 4; j++) {
        ao[(size_t)(orow + j) * HIDN + h * HD + dt * 16 + fr]      = (f16)(o0[dt][j] * iv0[j]);
        ao[(size_t)(orow + 16 + j) * HIDN + h * HD + dt * 16 + fr] = (f16)(o1[dt][j] * iv1[j]);
      }
  }
}

extern "C" void kernel_launch(void* const* d_in, const int* in_sizes, int n_in,
                              void* d_out, int out_size, void* d_ws, size_t ws_size,
                              hipStream_t stream) {
  const float* x      = (const float*)d_in[0];
  const int*   cu     = (const int*)d_in[1];
  const float* rpe    = (const float*)d_in[2];
  const float* qkv_w  = (const float*)d_in[3];
  const float* qkv_b  = (const float*)d_in[4];
  const float* proj_w = (const float*)d_in[5];
  const float* proj_b = (const float*)d_in[6];

  char* ws = (char*)d_ws;
  f16* xb    = (f16*)(ws);              // [4096][1280]
  f16* wqkv  = (f16*)(ws + 10485760);   // [3840][1280]
  f16* wproj = (f16*)(ws + 20316160);   // [1280][1280]
  f16* qkvb  = (f16*)(ws + 23592960);   // [4096][3840]
  f16* qh    = (f16*)(ws + 55050240);   // [16][4096][96]
  f16* kh    = (f16*)(ws + 67633152);   // [16][4096][96]
  f16* vt    = (f16*)(ws + 80216064);   // [16][80][4096] (kv-permuted)
  f16* ao    = xb;

  cvt_kernel<<<2560, 256, 0, stream>>>(x, xb, SEQ * HIDN);
  cvt_kernel<<<2400, 256, 0, stream>>>(qkv_w, wqkv, 3 * HIDN * HIDN);
  cvt_kernel<<<800, 256, 0, stream>>>(proj_w, wproj, HIDN * HIDN);

  qkv_gemm8<<<240, 512, 0, stream>>>(xb, wqkv, qkv_b, qkvb);

  rope_kernel<<<(SEQ * NH * 40) / 256, 256, 0, stream>>>(qkvb, rpe, qh, kh);
  vtrans_kernel<<<dim3(SEQ / 64, NH), 256, 0, stream>>>(qkvb, vt);

  attn_kernel<<<dim3(SEQ / 128, NH), 512, 0, stream>>>(qh, kh, vt, cu, ao);

  gemm_bt<1><<<dim3(HIDN / 128, SEQ / 128), 256, 0, stream>>>(
      ao, wproj, proj_b, d_out, SEQ, HIDN, HIDN);
}